// Round 1
// 1312.149 us; speedup vs baseline: 1.7227x; 1.7227x over previous
//
#include <hip/hip_runtime.h>

#define HW 16384
#define CH 256

// ---------------- depthwise 3x3, pad 1, per-channel (unchanged) ----------------
__global__ __launch_bounds__(256) void k_dw(const float* __restrict__ in,
                                            const float* __restrict__ w,
                                            float* __restrict__ out) {
  int bc = blockIdx.x;
  int c = bc & 255;
  float wv[9];
#pragma unroll
  for (int i = 0; i < 9; ++i) wv[i] = w[c * 9 + i];
  const float* ip = in + (size_t)bc * HW;
  float* op = out + (size_t)bc * HW;
  int t = threadIdx.x;
  for (int r = 0; r < 64; ++r) {
    int pix = r * 256 + t;
    int y = pix >> 7, x = pix & 127;
    float s = 0.f;
#pragma unroll
    for (int dy = 0; dy < 3; ++dy) {
      int yy = y + dy - 1;
      if (yy < 0 || yy > 127) continue;
#pragma unroll
      for (int dx = 0; dx < 3; ++dx) {
        int xx = x + dx - 1;
        if (xx < 0 || xx > 127) continue;
        s += wv[dy * 3 + dx] * ip[yy * 128 + xx];
      }
    }
    op[pix] = s;
  }
}

// ---------------- pointwise 1x1 as GEMM, 128x128 tile, 8x8/thread ----------------
// out[m][n] = sum_k Wt[m][k] * T[b][k][n]
// grid (N/128, M/128, B). blockIdx.y>>1 selects out buffer (fused qkv: M=768 -> 3 bufs).
__global__ __launch_bounds__(256) void k_pw(const float* __restrict__ T,
                                            const float* __restrict__ Wt,
                                            float* __restrict__ o0,
                                            float* __restrict__ o1,
                                            float* __restrict__ o2) {
  __shared__ __align__(16) float As[16][128];  // [k][m] transposed
  __shared__ __align__(16) float Bs[16][128];  // [k][n]
  int b = blockIdx.z;
  int n0 = blockIdx.x * 128;
  int gm0 = blockIdx.y * 128;
  int sel = blockIdx.y >> 1;
  float* outp = sel == 0 ? o0 : (sel == 1 ? o1 : o2);
  int lm0 = (blockIdx.y & 1) * 128;  // row within the selected 256-row buffer
  const float* Tb = T + (size_t)b * CH * HW;
  int t = threadIdx.x;
  int ty = t >> 4, tx = t & 15;
  int arow = t >> 1, af4 = (t & 1) * 2;  // A-load: 2 float4 per thread
  int bk = t >> 5, bf4 = t & 31;         // B-load: 2 float4 per thread
  float acc[8][8] = {};
  for (int k0 = 0; k0 < 256; k0 += 16) {
    __syncthreads();
#pragma unroll
    for (int ii = 0; ii < 2; ++ii) {
      float4 a4 = *(const float4*)(Wt + (size_t)(gm0 + arow) * 256 + k0 + (af4 + ii) * 4);
      As[(af4 + ii) * 4 + 0][arow] = a4.x;   // bank = arow%32: lanes t,t+1 share row -> 2-way (free)
      As[(af4 + ii) * 4 + 1][arow] = a4.y;
      As[(af4 + ii) * 4 + 2][arow] = a4.z;
      As[(af4 + ii) * 4 + 3][arow] = a4.w;
    }
#pragma unroll
    for (int ii = 0; ii < 2; ++ii) {       // lanes 0..31 contiguous 512B: coalesced + conflict-free
      *(float4*)&Bs[ii * 8 + bk][bf4 * 4] =
          *(const float4*)(Tb + (size_t)(k0 + ii * 8 + bk) * HW + n0 + bf4 * 4);
    }
    __syncthreads();
#pragma unroll
    for (int kk = 0; kk < 16; ++kk) {
      // a: broadcast (16 lanes same addr); b: slot = tx%8 -> conflict-free
      float4 a0 = *(const float4*)&As[kk][ty * 4];
      float4 a1 = *(const float4*)&As[kk][64 + ty * 4];
      float4 b0 = *(const float4*)&Bs[kk][tx * 4];
      float4 b1 = *(const float4*)&Bs[kk][64 + tx * 4];
      float av[8] = {a0.x, a0.y, a0.z, a0.w, a1.x, a1.y, a1.z, a1.w};
      float bv[8] = {b0.x, b0.y, b0.z, b0.w, b1.x, b1.y, b1.z, b1.w};
#pragma unroll
      for (int i = 0; i < 8; ++i)
#pragma unroll
        for (int j = 0; j < 8; ++j) acc[i][j] += av[i] * bv[j];
    }
  }
#pragma unroll
  for (int ih = 0; ih < 2; ++ih)
#pragma unroll
    for (int i = 0; i < 4; ++i) {
      int lrow = lm0 + ih * 64 + ty * 4 + i;
#pragma unroll
      for (int jh = 0; jh < 2; ++jh) {
        float4 o;
        o.x = acc[ih * 4 + i][jh * 4 + 0]; o.y = acc[ih * 4 + i][jh * 4 + 1];
        o.z = acc[ih * 4 + i][jh * 4 + 2]; o.w = acc[ih * 4 + i][jh * 4 + 3];
        *(float4*)(outp + ((size_t)b * CH + lrow) * HW + n0 + jh * 64 + tx * 4) = o;
      }
    }
}

// ---------------- 8x8 max pool: V layout [bh][cell][64] (as before) ----------------
__global__ __launch_bounds__(256) void k_pool(const float* __restrict__ src,
                                              float* __restrict__ dst) {
  int idx = blockIdx.x * 256 + threadIdx.x;
  int cell = idx & 255;
  int c = (idx >> 8) & 255;
  int b = idx >> 16;
  int sy = cell >> 4, sx = cell & 15;
  const float* sp = src + ((size_t)b * CH + c) * HW + (sy * 8) * 128 + sx * 8;
  float m = -1e30f;
#pragma unroll
  for (int iy = 0; iy < 8; ++iy) {
    float4 v0 = *(const float4*)(sp + iy * 128);
    float4 v1 = *(const float4*)(sp + iy * 128 + 4);
    m = fmaxf(m, fmaxf(fmaxf(v0.x, v0.y), fmaxf(v0.z, v0.w)));
    m = fmaxf(m, fmaxf(fmaxf(v1.x, v1.y), fmaxf(v1.z, v1.w)));
  }
  int dh = c >> 2, head = c & 3;
  dst[((size_t)(b * 4 + head) * 256 + cell) * 64 + dh] = m;
}

// ---------------- 8x8 max pool, K transposed layout [bh][d][cell] ----------------
// cell fastest across threads -> fully coalesced 4B writes (old layout scattered them)
__global__ __launch_bounds__(256) void k_poolT(const float* __restrict__ src,
                                               float* __restrict__ dst) {
  int idx = blockIdx.x * 256 + threadIdx.x;
  int cell = idx & 255;
  int c = (idx >> 8) & 255;
  int b = idx >> 16;
  int sy = cell >> 4, sx = cell & 15;
  const float* sp = src + ((size_t)b * CH + c) * HW + (sy * 8) * 128 + sx * 8;
  float m = -1e30f;
#pragma unroll
  for (int iy = 0; iy < 8; ++iy) {
    float4 v0 = *(const float4*)(sp + iy * 128);
    float4 v1 = *(const float4*)(sp + iy * 128 + 4);
    m = fmaxf(m, fmaxf(fmaxf(v0.x, v0.y), fmaxf(v0.z, v0.w)));
    m = fmaxf(m, fmaxf(fmaxf(v1.x, v1.y), fmaxf(v1.z, v1.w)));
  }
  int dh = c >> 2, head = c & 3;
  dst[((size_t)(b * 4 + head) * 64 + dh) * 256 + cell] = m;
}

// ---------------- attention: two register-tiled GEMMs through LDS ----------------
// q: [B][256][HW] planar (ch = dh*4+head); kp: [bh][64 d][256 cell]; vp: [bh][256 cell][64 d]
// Per block: 64 pixels x 256 keys. 256 thr.
// GEMM1 roles: ty=t>>4 pixel-group (4 pix), tx=t&15 key-group (keys qk*64+tx*4+j).
// GEMM2 roles: ty=d-group (4 d), tx=pixel-group (4 pix) -> direct full-line ao stores.
// LDS (40.25KB, 3 blocks/CU):
//   u1: Qs[64 d][64 pix] (GEMM1)  then P_c[64 key][65] bit-swapped cols (GEMM2)
//   u2: relc[2][31][65]  then Ks_c[64 d][64 key] / Vs_c[64 key][64 d]
//   rhw[64 pix][32]
__global__ __launch_bounds__(256, 3) void k_attn(
    const float* __restrict__ q, const float* __restrict__ kp,
    const float* __restrict__ vp, const float* __restrict__ relh,
    const float* __restrict__ relw, float* __restrict__ attn_o,
    float* __restrict__ ao) {
  int tile = blockIdx.x, head = blockIdx.y, b = blockIdx.z;
  int t = threadIdx.x;
  int pix0 = tile * 64;
  int bh = b * 4 + head;
  const size_t kvb = (size_t)bh * 16384;

  __shared__ __align__(16) float sm[10304];
  float* u1 = sm;            // 4160 floats
  float* u2 = sm + 4160;     // 4096 floats
  float* rhw = sm + 8256;    // 2048 floats

  int ty = t >> 4, tx = t & 15;

  // --- stage Qs[d][pix]: lanes 0-15 contiguous 64 floats of one channel row ---
  {
    int dq = t >> 4, f4 = t & 15;
#pragma unroll
    for (int i = 0; i < 4; ++i) {
      int d = i * 16 + dq;
      *(float4*)&u1[d * 64 + f4 * 4] =
          *(const float4*)(q + ((size_t)(b * CH + d * 4 + head)) * HW + pix0 + f4 * 4);
    }
  }
  // --- stage rel tables padded to stride 65 (row-stride != 0 mod 32 banks) ---
  for (int e = t; e < 3968; e += 256) {
    int tab = e >= 1984 ? 1 : 0;
    int e2 = tab ? e - 1984 : e;
    int row = e2 >> 6, d = e2 & 63;
    u2[tab * 2015 + row * 65 + d] = tab ? relw[e2] : relh[e2];
  }
  __syncthreads();

  // --- rel-pos logits: rhw[pix][m] = q[pix] . rel_row(m), m<16 keyed by hk, m>=16 by wk ---
  {
    int pp = t >> 2, mg = t & 3;
    int pixel = pix0 + pp;
    int y = pixel >> 7, x = pixel & 127;
    int ybase = 15 - (y >> 3), xbase = 15 - (x >> 3);
    int roff[8];
#pragma unroll
    for (int mm = 0; mm < 8; ++mm) {
      int m = mg * 8 + mm;
      roff[mm] = (m < 16) ? (m + ybase) * 65 : 2015 + (m - 16 + xbase) * 65;
    }
    float s[8] = {};
#pragma unroll 4
    for (int d = 0; d < 64; ++d) {
      float qv = u1[d * 64 + pp];
#pragma unroll
      for (int mm = 0; mm < 8; ++mm) s[mm] += qv * u2[roff[mm] + d];
    }
#pragma unroll
    for (int mm = 0; mm < 8; ++mm) rhw[pp * 32 + mg * 8 + mm] = s[mm];
  }

  // --- GEMM1: L[4 pix][16 key] over 4 key-chunks of 64 ---
  float L[4][16] = {};
#pragma unroll
  for (int qk = 0; qk < 4; ++qk) {
    __syncthreads();  // relc / previous Ks_c readers done
    {
      int dq = t >> 4, f4 = t & 15;
#pragma unroll
      for (int i = 0; i < 4; ++i) {
        int d = i * 16 + dq;
        *(float4*)&u2[d * 64 + f4 * 4] =
            *(const float4*)(kp + kvb + (size_t)d * 256 + qk * 64 + f4 * 4);
      }
    }
    __syncthreads();
#pragma unroll 8
    for (int d = 0; d < 64; ++d) {
      float4 qv = *(const float4*)&u1[d * 64 + ty * 4];   // broadcast over tx
      float4 kv4 = *(const float4*)&u2[d * 64 + tx * 4];  // slot = tx%8: conflict-free
      float qa[4] = {qv.x, qv.y, qv.z, qv.w};
      float ka[4] = {kv4.x, kv4.y, kv4.z, kv4.w};
#pragma unroll
      for (int i = 0; i < 4; ++i)
#pragma unroll
        for (int j = 0; j < 4; ++j) L[i][qk * 4 + j] += qa[i] * ka[j];
    }
  }

  // --- bias + softmax (rows = pixels; reduce over 16 tx lanes) ---
#pragma unroll
  for (int i = 0; i < 4; ++i) {
    int pp = ty * 4 + i;
    float m_ = -1e30f;
#pragma unroll
    for (int qk = 0; qk < 4; ++qk) {
      int hk = qk * 4 + (tx >> 2);          // key>>4 for all 4 j
      float gh = rhw[pp * 32 + hk];
#pragma unroll
      for (int j = 0; j < 4; ++j) {
        int wk = (tx * 4 + j) & 15;
        float v = (L[i][qk * 4 + j] + gh + rhw[pp * 32 + 16 + wk]) * 0.125f;
        L[i][qk * 4 + j] = v;
        m_ = fmaxf(m_, v);
      }
    }
    m_ = fmaxf(m_, __shfl_xor(m_, 1));
    m_ = fmaxf(m_, __shfl_xor(m_, 2));
    m_ = fmaxf(m_, __shfl_xor(m_, 4));
    m_ = fmaxf(m_, __shfl_xor(m_, 8));
    float s_ = 0.f;
#pragma unroll
    for (int k2 = 0; k2 < 16; ++k2) {
      float e = __expf(L[i][k2] - m_);
      L[i][k2] = e;
      s_ += e;
    }
    s_ += __shfl_xor(s_, 1);
    s_ += __shfl_xor(s_, 2);
    s_ += __shfl_xor(s_, 4);
    s_ += __shfl_xor(s_, 8);
    float inv = 1.f / s_;
#pragma unroll
    for (int k2 = 0; k2 < 16; ++k2) L[i][k2] *= inv;
  }

  // --- attn probs store: lanes 0-15 = consecutive key-float4s -> full 64B lines ---
#pragma unroll
  for (int i = 0; i < 4; ++i) {
    float* arow = attn_o + ((size_t)bh * HW + pix0 + ty * 4 + i) * 256 + tx * 4;
#pragma unroll
    for (int qk = 0; qk < 4; ++qk) {
      float4 o;
      o.x = L[i][qk * 4 + 0]; o.y = L[i][qk * 4 + 1];
      o.z = L[i][qk * 4 + 2]; o.w = L[i][qk * 4 + 3];
      *(float4*)(arow + qk * 64) = o;
    }
  }

  // --- GEMM2: O = P @ V via P-transpose in LDS ---
  // P_c[key][col'] with col' = ((pix&3)<<4)|(pix>>2), row stride 65:
  //   write bank = (4tx + ty + const) mod 32 -> 2-way (free); read: 16 consecutive banks.
  float acc2[4][4] = {};
#pragma unroll
  for (int qk = 0; qk < 4; ++qk) {
    __syncthreads();  // previous chunk consumed; also retires Qs (u1) on first iter
#pragma unroll
    for (int i = 0; i < 4; ++i) {  // stage Vs_c[cell][d]: straight 16KB copy, coalesced
      int idx = i * 256 + t;
      *(float4*)&u2[idx * 4] = *(const float4*)(vp + kvb + (size_t)qk * 4096 + idx * 4);
    }
#pragma unroll
    for (int i = 0; i < 4; ++i)    // P_c write (GEMM1 roles: ty=pix-group, tx=key-group)
#pragma unroll
      for (int j = 0; j < 4; ++j)
        u1[(tx * 4 + j) * 65 + i * 16 + ty] = L[i][qk * 4 + j];
    __syncthreads();
#pragma unroll 8
    for (int kk = 0; kk < 64; ++kk) {
      // GEMM2 roles: ty=d-group (V broadcast), tx=pix-group (P: 16 consecutive banks)
      float4 vv = *(const float4*)&u2[kk * 64 + ty * 4];
      float va[4] = {vv.x, vv.y, vv.z, vv.w};
      float pa[4];
#pragma unroll
      for (int i = 0; i < 4; ++i) pa[i] = u1[kk * 65 + i * 16 + tx];
#pragma unroll
      for (int dd = 0; dd < 4; ++dd)
#pragma unroll
        for (int i = 0; i < 4; ++i) acc2[dd][i] += pa[i] * va[dd];
    }
  }

  // --- ao store: float4 over 4 consecutive pixels, lanes 0-15 contiguous 256B ---
#pragma unroll
  for (int dd = 0; dd < 4; ++dd) {
    int ch = (ty * 4 + dd) * 4 + head;
    float4 o;
    o.x = acc2[dd][0]; o.y = acc2[dd][1]; o.z = acc2[dd][2]; o.w = acc2[dd][3];
    *(float4*)(ao + ((size_t)b * CH + ch) * HW + pix0 + tx * 4) = o;
  }
}

extern "C" void kernel_launch(void* const* d_in, const int* in_sizes, int n_in,
                              void* d_out, int out_size, void* d_ws, size_t ws_size,
                              hipStream_t stream) {
  const float* x   = (const float*)d_in[0];
  const float* dw1 = (const float*)d_in[1];
  const float* pw1 = (const float*)d_in[2];
  const float* krw = (const float*)d_in[3];
  const float* krh = (const float*)d_in[4];
  const float* dw2 = (const float*)d_in[5];
  const float* pw2 = (const float*)d_in[6];

  float* out = (float*)d_out;                      // [B][256][HW], 16,777,216
  float* attnbuf = out + (size_t)16777216;         // [B*4][HW][256], 67,108,864

  // scratch inside d_out's attn region (dead until k_attn writes it):
  float* t1    = attnbuf;                          // dw1 out          (16.7M)
  float* kfull = attnbuf + (size_t)16777216;       // k full-res       (16.7M)
  float* vfull = attnbuf + (size_t)33554432;       // v full-res       (16.7M)
  // d_ws (f32): q/t2 (16,777,216) + kp (262,144) + vp (262,144)
  float* qb = (float*)d_ws;
  float* kp = qb + (size_t)16777216;               // [bh][64 d][256 cell]
  float* vp = kp + (size_t)262144;                 // [bh][256 cell][64 d]
  float* t2 = qb;                                  // reuse q region after attn

  dim3 b256(256);
  k_dw<<<dim3(1024), b256, 0, stream>>>(x, dw1, t1);
  // fused q/k/v pointwise: M=768 -> grid y=6; y>>1 selects {q,k,v} buffer
  k_pw<<<dim3(128, 6, 4), b256, 0, stream>>>(t1, pw1, qb, kfull, vfull);
  k_poolT<<<dim3(1024), b256, 0, stream>>>(kfull, kp);
  k_pool<<<dim3(1024), b256, 0, stream>>>(vfull, vp);
  k_attn<<<dim3(256, 4, 4), b256, 0, stream>>>(qb, kp, vp, krh, krw, attnbuf, out);
  k_dw<<<dim3(1024), b256, 0, stream>>>(out, dw2, t2);
  k_pw<<<dim3(128, 2, 4), b256, 0, stream>>>(t2, pw2, out, out, out);
}